// Round 15
// baseline (400.922 us; speedup 1.0000x reference)
//
#include <hip/hip_runtime.h>
#include <hip/hip_fp16.h>

#define N_NODES 50000
#define N_EDGES 800000
#define CEILDIV(a,b) (((a)+(b)-1)/(b))
#define NB_SCAN CEILDIV(N_NODES, 256)   // 196 blocks
#define NHALF   (N_NODES / 2)           // 25000

typedef _Float16 half8 __attribute__((ext_vector_type(8)));
typedef float    f32x4 __attribute__((ext_vector_type(4)));

// ---------------------------------------------------------------------------
// CSR build — 4 edges per thread (int4 loads, independent chains)
// ---------------------------------------------------------------------------
__global__ __launch_bounds__(256) void k_deg4(const int* __restrict__ dst,
                                              int* __restrict__ degcnt, int e4) {
    int i = blockIdx.x * 256 + threadIdx.x;
    if (i < e4) {
        int4 d4 = ((const int4*)dst)[i];
        atomicAdd(&degcnt[d4.x], 1);
        atomicAdd(&degcnt[d4.y], 1);
        atomicAdd(&degcnt[d4.z], 1);
        atomicAdd(&degcnt[d4.w], 1);
    }
}

__global__ __launch_bounds__(256) void k_blocksum(const int* __restrict__ degcnt,
                                                  int* __restrict__ bsum, int n) {
    __shared__ int part[256];
    const int tid = threadIdx.x;
    const int gid = blockIdx.x * 256 + tid;
    part[tid] = (gid < n) ? degcnt[gid] : 0;
    __syncthreads();
    for (int off = 128; off > 0; off >>= 1) {
        if (tid < off) part[tid] += part[tid + off];
        __syncthreads();
    }
    if (tid == 0) bsum[blockIdx.x] = part[0];
}

__global__ __launch_bounds__(256) void k_scanb(const int* __restrict__ bsum,
                                               int* __restrict__ boff) {
    __shared__ int part[256];
    const int tid = threadIdx.x;
    part[tid] = (tid < NB_SCAN) ? bsum[tid] : 0;
    __syncthreads();
    for (int off = 1; off < 256; off <<= 1) {
        int v = (tid >= off) ? part[tid - off] : 0;
        __syncthreads();
        part[tid] += v;
        __syncthreads();
    }
    if (tid < NB_SCAN) boff[tid] = (tid == 0) ? 0 : part[tid - 1];
}

__global__ __launch_bounds__(256) void k_rowstart(const int* __restrict__ degcnt,
                                                  const int* __restrict__ boff,
                                                  int* __restrict__ rowstart,
                                                  float* __restrict__ dinv, int n) {
    __shared__ int part[256];
    const int tid = threadIdx.x;
    const int gid = blockIdx.x * 256 + tid;
    const int d = (gid < n) ? degcnt[gid] : 0;
    part[tid] = d;
    __syncthreads();
    for (int off = 1; off < 256; off <<= 1) {
        int v = (tid >= off) ? part[tid - off] : 0;
        __syncthreads();
        part[tid] += v;
        __syncthreads();
    }
    if (gid < n) {
        rowstart[gid] = boff[blockIdx.x] + part[tid] - d;   // exclusive
        dinv[gid] = rsqrtf((float)(d + 1));                 // +1 self loop
    }
    if (gid == 0) rowstart[n] = N_EDGES;
}

__global__ __launch_bounds__(256) void k_bin4(const int* __restrict__ src,
                                              const int* __restrict__ dst,
                                              const int* __restrict__ rowstart,
                                              int* __restrict__ cursor,
                                              int* __restrict__ esrc, int e4) {
    int i = blockIdx.x * 256 + threadIdx.x;
    if (i >= e4) return;
    int4 s4 = ((const int4*)src)[i];
    int4 d4 = ((const int4*)dst)[i];
    int r0 = rowstart[d4.x];
    int r1 = rowstart[d4.y];
    int r2 = rowstart[d4.z];
    int r3 = rowstart[d4.w];
    int p0 = atomicAdd(&cursor[d4.x], 1);
    int p1 = atomicAdd(&cursor[d4.y], 1);
    int p2 = atomicAdd(&cursor[d4.z], 1);
    int p3 = atomicAdd(&cursor[d4.w], 1);
    __builtin_nontemporal_store(s4.x, &esrc[r0 + p0]);
    __builtin_nontemporal_store(s4.y, &esrc[r1 + p1]);
    __builtin_nontemporal_store(s4.z, &esrc[r2 + p2]);
    __builtin_nontemporal_store(s4.w, &esrc[r3 + p3]);
}

// ---------------------------------------------------------------------------
// one-time casts
// ---------------------------------------------------------------------------
__global__ __launch_bounds__(256) void k_x2h(const float* __restrict__ x,
                                             __half* __restrict__ xh, long total) {
    long i = (long)(blockIdx.x * 256 + threadIdx.x) * 8;
    if (i >= total) return;
    float4 lo = ((const float4*)x)[i / 4];
    float4 hi = ((const float4*)x)[i / 4 + 1];
    union { __half2 h2[4]; uint4 u; } pk;
    pk.h2[0] = __floats2half2_rn(lo.x, lo.y);
    pk.h2[1] = __floats2half2_rn(lo.z, lo.w);
    pk.h2[2] = __floats2half2_rn(hi.x, hi.y);
    pk.h2[3] = __floats2half2_rn(hi.z, hi.w);
    ((uint4*)xh)[i / 8] = pk.u;
}

// all three W -> W^T fp16 casts in one launch (40960 elements)
__global__ __launch_bounds__(256) void k_wcast(const float* __restrict__ W1,
                                               const float* __restrict__ W2,
                                               const float* __restrict__ W3,
                                               __half* __restrict__ wt1,
                                               __half* __restrict__ wt2,
                                               __half* __restrict__ wt3) {
    int idx = blockIdx.x * 256 + threadIdx.x;
    if (idx < 16384) {
        int c = idx >> 7, k = idx & 127;
        wt1[c * 128 + k] = __float2half(W1[(size_t)k * 128 + c]);
    } else if (idx < 32768) {
        int j = idx - 16384;
        int c = j >> 7, k = j & 127;
        wt2[c * 128 + k] = __float2half(W2[(size_t)k * 128 + c]);
    } else if (idx < 40960) {
        int j = idx - 32768;
        int c = j >> 7, k = j & 127;
        wt3[c * 128 + k] = __float2half(W3[(size_t)k * 64 + c]);
    }
}

// ---------------------------------------------------------------------------
// MFMA GEMM. A fp16 [n][128] (SIN=0) or sliced [4][n][32] (SIN=1).
// C fp16 sliced [4][n][32] (SOUT=1, KOUT=128) or normal [n][KOUT] (SOUT=0).
// ---------------------------------------------------------------------------
template<int KOUT, bool RELU, bool SIN, bool SOUT>
__global__ __launch_bounds__(256) void k_gemm(const __half* __restrict__ A,
                                              const __half* __restrict__ Wt,
                                              const float* __restrict__ dinv,
                                              __half* __restrict__ C, int n) {
    constexpr int NT     = KOUT / 16;
    constexpr int ABYTES = 64 * 256;
    constexpr int WBYTES = KOUT * 256;
    __shared__ uint4 ldsbuf[(ABYTES + WBYTES) / 16];
    char* Als = (char*)ldsbuf;
    char* Wls = Als + ABYTES;

    const int tid  = threadIdx.x;
    const int row0 = blockIdx.x * 64;

    // ---- stage A tile (64 rows x 256B), fused ReLU, swizzled ----
#pragma unroll
    for (int i = 0; i < 4; ++i) {
        int g   = tid + i * 256;
        int r   = g >> 4;
        int ch  = g & 15;                    // 16B chunk in row (col ch*8..ch*8+7)
        int gr  = row0 + r;
        uint4 v = make_uint4(0u, 0u, 0u, 0u);
        if (gr < n) {
            if (SIN) {
                int sl = ch >> 2, c2 = ch & 3;   // slice, chunk-in-slice
                v = ((const uint4*)A)[((size_t)sl * n + gr) * 4 + c2];
            } else {
                v = ((const uint4*)A)[(size_t)gr * 16 + ch];
            }
        }
        if (RELU) {
            uint n0 = (v.x >> 15) & 0x00010001u; v.x &= ~(n0 * 0xFFFFu);
            uint n1 = (v.y >> 15) & 0x00010001u; v.y &= ~(n1 * 0xFFFFu);
            uint n2 = (v.z >> 15) & 0x00010001u; v.z &= ~(n2 * 0xFFFFu);
            uint n3 = (v.w >> 15) & 0x00010001u; v.w &= ~(n3 * 0xFFFFu);
        }
        *(uint4*)(Als + r * 256 + ((ch * 16) ^ ((r & 7) << 4))) = v;
    }
    // ---- stage W^T (KOUT rows x 256B), swizzled ----
#pragma unroll
    for (int i = 0; i < WBYTES / 16 / 256; ++i) {
        int g  = tid + i * 256;
        int r  = g >> 4;
        int ch = g & 15;
        uint4 v = ((const uint4*)Wt)[(size_t)r * 16 + ch];
        *(uint4*)(Wls + r * 256 + ((ch * 16) ^ ((r & 7) << 4))) = v;
    }
    __syncthreads();

    const int wave = tid >> 6;
    const int lane = tid & 63;
    const int l15  = lane & 15;
    const int l4   = lane >> 4;

    f32x4 acc[NT];
#pragma unroll
    for (int ct = 0; ct < NT; ++ct) acc[ct] = (f32x4){0.f, 0.f, 0.f, 0.f};

#pragma unroll
    for (int kb = 0; kb < 4; ++kb) {
        const int arow = 16 * wave + l15;
        half8 af = *(half8*)(Als + arow * 256 +
                             (((kb * 64) + l4 * 16) ^ ((arow & 7) << 4)));
#pragma unroll
        for (int ct = 0; ct < NT; ++ct) {
            const int wrow = ct * 16 + l15;
            half8 bf = *(half8*)(Wls + wrow * 256 +
                                 (((kb * 64) + l4 * 16) ^ ((wrow & 7) << 4)));
            acc[ct] = __builtin_amdgcn_mfma_f32_16x16x32_f16(af, bf, acc[ct], 0, 0, 0);
        }
    }

    // ---- epilogue: dinv-scale, fp16 stores ----
    const int rbase = row0 + 16 * wave + l4 * 4;
    const float d0 = dinv[min(rbase + 0, n - 1)];
    const float d1 = dinv[min(rbase + 1, n - 1)];
    const float d2 = dinv[min(rbase + 2, n - 1)];
    const float d3 = dinv[min(rbase + 3, n - 1)];
#pragma unroll
    for (int ct = 0; ct < NT; ++ct) {
        size_t p0, p1, p2, p3;
        if (SOUT) {
            const size_t sb = ((size_t)(ct >> 1) * n) * 32 + (ct & 1) * 16 + l15;
            p0 = sb + (size_t)(rbase + 0) * 32;
            p1 = sb + (size_t)(rbase + 1) * 32;
            p2 = sb + (size_t)(rbase + 2) * 32;
            p3 = sb + (size_t)(rbase + 3) * 32;
        } else {
            const int col = ct * 16 + l15;
            p0 = (size_t)(rbase + 0) * KOUT + col;
            p1 = (size_t)(rbase + 1) * KOUT + col;
            p2 = (size_t)(rbase + 2) * KOUT + col;
            p3 = (size_t)(rbase + 3) * KOUT + col;
        }
        if (rbase + 0 < n) C[p0] = __float2half(acc[ct][0] * d0);
        if (rbase + 1 < n) C[p1] = __float2half(acc[ct][1] * d1);
        if (rbase + 2 < n) C[p2] = __float2half(acc[ct][2] * d2);
        if (rbase + 3 < n) C[p3] = __float2half(acc[ct][3] * d3);
    }
}

// ---------------------------------------------------------------------------
// SLICED aggregation (K=128, layers 1-2): h sliced [4][n][32] fp16.
// blockIdx%8 -> XCD; slice = xcd%4 (3.2MB working set fits 4MB L2),
// node-half = xcd/4. One node-slice per 32-lane group; lane owns 1 col.
//   out[s][d][c] = dinv[d]*( h[s][d][c] + sum_{e:dst=d} h[s][src_e][c] ) + b[s*32+c]
// ---------------------------------------------------------------------------
__global__ __launch_bounds__(256) void k_agg_sl(const __half* __restrict__ h,
                                                const int* __restrict__ rowstart,
                                                const int* __restrict__ esrc,
                                                const float* __restrict__ dinv,
                                                const float* __restrict__ b,
                                                __half* __restrict__ out, int n) {
    const int tid  = threadIdx.x;
    const int l5   = tid & 31;
    const int base = tid & 32;             // shfl base of this 32-lane group
    const int b8   = blockIdx.x & 7;       // ~XCD id
    const int s    = b8 & 3;               // column slice
    const int half = b8 >> 2;              // node half
    const int node = half * NHALF + (blockIdx.x >> 3) * 8 + (tid >> 5);
    if (node >= n) return;

    const __half* hs = h + (size_t)s * n * 32;

    float acc = __half2float(hs[(size_t)node * 32 + l5]);   // self-loop term

    int row = rowstart[node];
    const int end = rowstart[node + 1];

#define G1(S_, OK_)                                                        \
    {                                                                      \
        float v_ = 0.f;                                                    \
        if (OK_) v_ = __half2float(hs[(size_t)(S_) * 32 + l5]);            \
        acc += v_;                                                         \
    }

    while (row < end) {
        int cnt = end - row;
        if (cnt > 32) cnt = 32;
        int s_l = (l5 < cnt) ? esrc[row + l5] : 0;
        for (int jj = 0; jj < cnt; jj += 8) {
            const int i0 = jj + 0, i1 = jj + 1, i2 = jj + 2, i3 = jj + 3;
            const int i4 = jj + 4, i5 = jj + 5, i6 = jj + 6, i7 = jj + 7;
            const int s0 = __shfl(s_l, base + i0);
            const int s1 = __shfl(s_l, base + i1);
            const int s2 = __shfl(s_l, base + i2);
            const int s3 = __shfl(s_l, base + i3);
            const int s4 = __shfl(s_l, base + i4);
            const int s5 = __shfl(s_l, base + i5);
            const int s6 = __shfl(s_l, base + i6);
            const int s7 = __shfl(s_l, base + i7);
            G1(s0, i0 < cnt);
            G1(s1, i1 < cnt);
            G1(s2, i2 < cnt);
            G1(s3, i3 < cnt);
            G1(s4, i4 < cnt);
            G1(s5, i5 < cnt);
            G1(s6, i6 < cnt);
            G1(s7, i7 < cnt);
        }
        row += cnt;
    }
#undef G1

    const float o = acc * dinv[node] + b[s * 32 + l5];
    out[(size_t)s * n * 32 + (size_t)node * 32 + l5] = __float2half(o);
}

// ---------------------------------------------------------------------------
// Final aggregation (K=64, layer 3): h normal [n][64] fp16, out f32 [n][64].
// One node per 32-lane group, lane owns 2 cols (uint = half2), 8-deep batch.
// ---------------------------------------------------------------------------
__global__ __launch_bounds__(256) void k_agg64(const __half* __restrict__ h,
                                               const int* __restrict__ rowstart,
                                               const int* __restrict__ esrc,
                                               const float* __restrict__ dinv,
                                               const float* __restrict__ b,
                                               float* __restrict__ out, int n) {
    const int tid  = threadIdx.x;
    const int l5   = tid & 31;
    const int base = tid & 32;
    const int node = blockIdx.x * 8 + (tid >> 5);
    if (node >= n) return;

    float a0, a1;
    {
        uint raw = ((const uint*)h)[(size_t)node * 32 + l5];
        union { uint u; __half2 h2; } c; c.u = raw;
        float2 lo = __half22float2(c.h2);
        a0 = lo.x; a1 = lo.y;
    }

    int row = rowstart[node];
    const int end = rowstart[node + 1];

#define G2(S_, OK_)                                                        \
    {                                                                      \
        uint raw = 0u;                                                     \
        if (OK_) raw = ((const uint*)h)[(size_t)(S_) * 32 + l5];           \
        union { uint u; __half2 h2; } c; c.u = raw;                        \
        float2 lo = __half22float2(c.h2);                                  \
        a0 += lo.x; a1 += lo.y;                                            \
    }

    while (row < end) {
        int cnt = end - row;
        if (cnt > 32) cnt = 32;
        int s_l = (l5 < cnt) ? esrc[row + l5] : 0;
        for (int jj = 0; jj < cnt; jj += 8) {
            const int i0 = jj + 0, i1 = jj + 1, i2 = jj + 2, i3 = jj + 3;
            const int i4 = jj + 4, i5 = jj + 5, i6 = jj + 6, i7 = jj + 7;
            const int s0 = __shfl(s_l, base + i0);
            const int s1 = __shfl(s_l, base + i1);
            const int s2 = __shfl(s_l, base + i2);
            const int s3 = __shfl(s_l, base + i3);
            const int s4 = __shfl(s_l, base + i4);
            const int s5 = __shfl(s_l, base + i5);
            const int s6 = __shfl(s_l, base + i6);
            const int s7 = __shfl(s_l, base + i7);
            G2(s0, i0 < cnt);
            G2(s1, i1 < cnt);
            G2(s2, i2 < cnt);
            G2(s3, i3 < cnt);
            G2(s4, i4 < cnt);
            G2(s5, i5 < cnt);
            G2(s6, i6 < cnt);
            G2(s7, i7 < cnt);
        }
        row += cnt;
    }
#undef G2

    const float dd = dinv[node];
    float2 bb = ((const float2*)b)[l5];
    ((float2*)out)[(size_t)node * 32 + l5] =
        make_float2(a0 * dd + bb.x, a1 * dd + bb.y);
}

// ---------------------------------------------------------------------------
extern "C" void kernel_launch(void* const* d_in, const int* in_sizes, int n_in,
                              void* d_out, int out_size, void* d_ws, size_t ws_size,
                              hipStream_t stream) {
    const float* x  = (const float*)d_in[0];
    const int*   ei = (const int*)d_in[1];
    const float* W1 = (const float*)d_in[2];
    const float* b1 = (const float*)d_in[3];
    const float* W2 = (const float*)d_in[4];
    const float* b2 = (const float*)d_in[5];
    const float* W3 = (const float*)d_in[6];
    const float* b3 = (const float*)d_in[7];
    float* out = (float*)d_out;

    const int* src = ei;
    const int* dst = ei + N_EDGES;

    char* ws = (char*)d_ws;
    size_t off = 0;
    auto alloc = [&](size_t bytes) {
        void* p = ws + off;
        off += (bytes + 255) & ~(size_t)255;
        return p;
    };
    int*    degcnt   = (int*)alloc((size_t)N_NODES * 2 * 4);  // degcnt + cursor
    int*    cursor   = degcnt + N_NODES;
    int*    rowstart = (int*)alloc((N_NODES + 1) * 4);
    float*  dinv     = (float*)alloc(N_NODES * 4);
    int*    bsum     = (int*)alloc(NB_SCAN * 4);
    int*    boff     = (int*)alloc(NB_SCAN * 4);
    int*    esrc     = (int*)alloc((size_t)N_EDGES * 4);
    __half* xh       = (__half*)alloc((size_t)N_NODES * 128 * 2);
    __half* hbuf     = (__half*)alloc((size_t)N_NODES * 128 * 2);  // sliced h' / hbuf3
    __half* abuf     = (__half*)alloc((size_t)N_NODES * 128 * 2);  // sliced activations
    __half* wt1      = (__half*)alloc(128 * 128 * 2);
    __half* wt2      = (__half*)alloc(128 * 128 * 2);
    __half* wt3      = (__half*)alloc(64 * 128 * 2);

    const int n = N_NODES, e = N_EDGES;

    // --- CSR build (once; reused by all layers) ---
    hipMemsetAsync(degcnt, 0, (size_t)N_NODES * 2 * 4, stream);
    k_deg4<<<CEILDIV(e / 4, 256), 256, 0, stream>>>(dst, degcnt, e / 4);
    k_blocksum<<<NB_SCAN, 256, 0, stream>>>(degcnt, bsum, n);
    k_scanb<<<1, 256, 0, stream>>>(bsum, boff);
    k_rowstart<<<NB_SCAN, 256, 0, stream>>>(degcnt, boff, rowstart, dinv, n);
    k_bin4<<<CEILDIV(e / 4, 256), 256, 0, stream>>>(src, dst, rowstart, cursor, esrc, e / 4);

    // --- one-time fp16 casts ---
    k_x2h<<<CEILDIV((long)n * 128, 8 * 256), 256, 0, stream>>>(x, xh, (long)n * 128);
    k_wcast<<<CEILDIV(40960, 256), 256, 0, stream>>>(W1, W2, W3, wt1, wt2, wt3);

    const int aggblocks = (NHALF / 8) * 8;   // 3125 node-blocks x 8 (slice,half)

    // --- layer 1: gemm (normal in, sliced out) ; sliced aggregate ---
    k_gemm<128, false, false, true><<<CEILDIV(n, 64), 256, 0, stream>>>(xh, wt1, dinv, hbuf, n);
    k_agg_sl<<<aggblocks, 256, 0, stream>>>(hbuf, rowstart, esrc, dinv, b1, abuf, n);

    // --- layer 2: gemm (sliced in, sliced out) ; sliced aggregate ---
    k_gemm<128, true, true, true><<<CEILDIV(n, 64), 256, 0, stream>>>(abuf, wt2, dinv, hbuf, n);
    k_agg_sl<<<aggblocks, 256, 0, stream>>>(hbuf, rowstart, esrc, dinv, b2, abuf, n);

    // --- layer 3: gemm (sliced in, normal out K=64) ; final aggregate f32 ---
    k_gemm<64, true, true, false><<<CEILDIV(n, 64), 256, 0, stream>>>(abuf, wt3, dinv, hbuf, n);
    k_agg64<<<CEILDIV(n, 8), 256, 0, stream>>>(hbuf, rowstart, esrc, dinv, b3, out, n);
}

// Round 16
// 279.576 us; speedup vs baseline: 1.4340x; 1.4340x over previous
//
#include <hip/hip_runtime.h>
#include <hip/hip_fp16.h>

#define N_NODES 50000
#define N_EDGES 800000
#define CEILDIV(a,b) (((a)+(b)-1)/(b))
#define NB_SCAN CEILDIV(N_NODES, 256)   // 196 blocks
#define NPART   8
#define PSIZE   CEILDIV(N_NODES, NPART) // 6250 nodes per dst-partition

typedef _Float16 half8 __attribute__((ext_vector_type(8)));
typedef float    f32x4 __attribute__((ext_vector_type(4)));

// ---------------------------------------------------------------------------
// CSR build — dst-range partitioned: block b handles only dst in partition
// b&7 (single-writer-XCD lines -> no cross-XCD write bouncing), 4 edges/thread.
// ---------------------------------------------------------------------------
__global__ __launch_bounds__(256) void k_deg4p(const int* __restrict__ dst,
                                               int* __restrict__ degcnt, int e4) {
    const int part = blockIdx.x & 7;
    const int lo = part * PSIZE, hi = lo + PSIZE;
    int i = (blockIdx.x >> 3) * 256 + threadIdx.x;
    if (i >= e4) return;
    int4 d4 = ((const int4*)dst)[i];
    if (d4.x >= lo && d4.x < hi) atomicAdd(&degcnt[d4.x], 1);
    if (d4.y >= lo && d4.y < hi) atomicAdd(&degcnt[d4.y], 1);
    if (d4.z >= lo && d4.z < hi) atomicAdd(&degcnt[d4.z], 1);
    if (d4.w >= lo && d4.w < hi) atomicAdd(&degcnt[d4.w], 1);
}

__global__ __launch_bounds__(256) void k_blocksum(const int* __restrict__ degcnt,
                                                  int* __restrict__ bsum, int n) {
    __shared__ int part[256];
    const int tid = threadIdx.x;
    const int gid = blockIdx.x * 256 + tid;
    part[tid] = (gid < n) ? degcnt[gid] : 0;
    __syncthreads();
    for (int off = 128; off > 0; off >>= 1) {
        if (tid < off) part[tid] += part[tid + off];
        __syncthreads();
    }
    if (tid == 0) bsum[blockIdx.x] = part[0];
}

__global__ __launch_bounds__(256) void k_scanb(const int* __restrict__ bsum,
                                               int* __restrict__ boff) {
    __shared__ int part[256];
    const int tid = threadIdx.x;
    part[tid] = (tid < NB_SCAN) ? bsum[tid] : 0;
    __syncthreads();
    for (int off = 1; off < 256; off <<= 1) {
        int v = (tid >= off) ? part[tid - off] : 0;
        __syncthreads();
        part[tid] += v;
        __syncthreads();
    }
    if (tid < NB_SCAN) boff[tid] = (tid == 0) ? 0 : part[tid - 1];
}

__global__ __launch_bounds__(256) void k_rowstart(const int* __restrict__ degcnt,
                                                  const int* __restrict__ boff,
                                                  int* __restrict__ rowstart,
                                                  float* __restrict__ dinv, int n) {
    __shared__ int part[256];
    const int tid = threadIdx.x;
    const int gid = blockIdx.x * 256 + tid;
    const int d = (gid < n) ? degcnt[gid] : 0;
    part[tid] = d;
    __syncthreads();
    for (int off = 1; off < 256; off <<= 1) {
        int v = (tid >= off) ? part[tid - off] : 0;
        __syncthreads();
        part[tid] += v;
        __syncthreads();
    }
    if (gid < n) {
        rowstart[gid] = boff[blockIdx.x] + part[tid] - d;   // exclusive
        dinv[gid] = rsqrtf((float)(d + 1));                 // +1 self loop
    }
    if (gid == 0) rowstart[n] = N_EDGES;
}

__global__ __launch_bounds__(256) void k_bin4p(const int* __restrict__ src,
                                               const int* __restrict__ dst,
                                               const int* __restrict__ rowstart,
                                               int* __restrict__ cursor,
                                               int* __restrict__ esrc, int e4) {
    const int part = blockIdx.x & 7;
    const int lo = part * PSIZE, hi = lo + PSIZE;
    int i = (blockIdx.x >> 3) * 256 + threadIdx.x;
    if (i >= e4) return;
    int4 s4 = ((const int4*)src)[i];
    int4 d4 = ((const int4*)dst)[i];
    if (d4.x >= lo && d4.x < hi) {
        int p = rowstart[d4.x] + atomicAdd(&cursor[d4.x], 1);
        __builtin_nontemporal_store(s4.x, &esrc[p]);
    }
    if (d4.y >= lo && d4.y < hi) {
        int p = rowstart[d4.y] + atomicAdd(&cursor[d4.y], 1);
        __builtin_nontemporal_store(s4.y, &esrc[p]);
    }
    if (d4.z >= lo && d4.z < hi) {
        int p = rowstart[d4.z] + atomicAdd(&cursor[d4.z], 1);
        __builtin_nontemporal_store(s4.z, &esrc[p]);
    }
    if (d4.w >= lo && d4.w < hi) {
        int p = rowstart[d4.w] + atomicAdd(&cursor[d4.w], 1);
        __builtin_nontemporal_store(s4.w, &esrc[p]);
    }
}

// ---------------------------------------------------------------------------
// all three W -> W^T fp16 casts in one launch (40960 elements)
// ---------------------------------------------------------------------------
__global__ __launch_bounds__(256) void k_wcast(const float* __restrict__ W1,
                                               const float* __restrict__ W2,
                                               const float* __restrict__ W3,
                                               __half* __restrict__ wt1,
                                               __half* __restrict__ wt2,
                                               __half* __restrict__ wt3) {
    int idx = blockIdx.x * 256 + threadIdx.x;
    if (idx < 16384) {
        int c = idx >> 7, k = idx & 127;
        wt1[c * 128 + k] = __float2half(W1[(size_t)k * 128 + c]);
    } else if (idx < 32768) {
        int j = idx - 16384;
        int c = j >> 7, k = j & 127;
        wt2[c * 128 + k] = __float2half(W2[(size_t)k * 128 + c]);
    } else if (idx < 40960) {
        int j = idx - 32768;
        int c = j >> 7, k = j & 127;
        wt3[c * 128 + k] = __float2half(W3[(size_t)k * 64 + c]);
    }
}

// ---------------------------------------------------------------------------
// MFMA GEMM: C[i][:] = fp16( op(A)[i][0..127] @ W * dinv[i] )
// CVT=1: A is f32 (layer 1, cast fused into staging). Else A fp16 [n][128].
// ---------------------------------------------------------------------------
template<int KOUT, bool RELU, bool CVT>
__global__ __launch_bounds__(256) void k_gemm(const void* __restrict__ Ain,
                                              const __half* __restrict__ Wt,
                                              const float* __restrict__ dinv,
                                              __half* __restrict__ C, int n) {
    constexpr int NT     = KOUT / 16;
    constexpr int ABYTES = 64 * 256;
    constexpr int WBYTES = KOUT * 256;
    __shared__ uint4 ldsbuf[(ABYTES + WBYTES) / 16];
    char* Als = (char*)ldsbuf;
    char* Wls = Als + ABYTES;

    const int tid  = threadIdx.x;
    const int row0 = blockIdx.x * 64;

    // ---- stage A tile (64 rows x 128 fp16), fused ReLU/cast, swizzled ----
#pragma unroll
    for (int i = 0; i < 4; ++i) {
        int g   = tid + i * 256;
        int r   = g >> 4;
        int ch  = g & 15;                    // 16B chunk (cols ch*8..ch*8+7)
        int gr  = row0 + r;
        uint4 v = make_uint4(0u, 0u, 0u, 0u);
        if (gr < n) {
            if (CVT) {
                const float4* Af = (const float4*)Ain;
                float4 flo = Af[(size_t)gr * 32 + ch * 2];
                float4 fhi = Af[(size_t)gr * 32 + ch * 2 + 1];
                union { __half2 h2[4]; uint4 u; } pk;
                pk.h2[0] = __floats2half2_rn(flo.x, flo.y);
                pk.h2[1] = __floats2half2_rn(flo.z, flo.w);
                pk.h2[2] = __floats2half2_rn(fhi.x, fhi.y);
                pk.h2[3] = __floats2half2_rn(fhi.z, fhi.w);
                v = pk.u;
            } else {
                v = ((const uint4*)Ain)[(size_t)gr * 16 + ch];
            }
        }
        if (RELU) {
            uint n0 = (v.x >> 15) & 0x00010001u; v.x &= ~(n0 * 0xFFFFu);
            uint n1 = (v.y >> 15) & 0x00010001u; v.y &= ~(n1 * 0xFFFFu);
            uint n2 = (v.z >> 15) & 0x00010001u; v.z &= ~(n2 * 0xFFFFu);
            uint n3 = (v.w >> 15) & 0x00010001u; v.w &= ~(n3 * 0xFFFFu);
        }
        *(uint4*)(Als + r * 256 + ((ch * 16) ^ ((r & 7) << 4))) = v;
    }
    // ---- stage W^T (KOUT rows x 256B), swizzled ----
#pragma unroll
    for (int i = 0; i < WBYTES / 16 / 256; ++i) {
        int g  = tid + i * 256;
        int r  = g >> 4;
        int ch = g & 15;
        uint4 v = ((const uint4*)Wt)[(size_t)r * 16 + ch];
        *(uint4*)(Wls + r * 256 + ((ch * 16) ^ ((r & 7) << 4))) = v;
    }
    __syncthreads();

    const int wave = tid >> 6;
    const int lane = tid & 63;
    const int l15  = lane & 15;
    const int l4   = lane >> 4;

    f32x4 acc[NT];
#pragma unroll
    for (int ct = 0; ct < NT; ++ct) acc[ct] = (f32x4){0.f, 0.f, 0.f, 0.f};

#pragma unroll
    for (int kb = 0; kb < 4; ++kb) {
        const int arow = 16 * wave + l15;
        half8 af = *(half8*)(Als + arow * 256 +
                             (((kb * 64) + l4 * 16) ^ ((arow & 7) << 4)));
#pragma unroll
        for (int ct = 0; ct < NT; ++ct) {
            const int wrow = ct * 16 + l15;
            half8 bf = *(half8*)(Wls + wrow * 256 +
                                 (((kb * 64) + l4 * 16) ^ ((wrow & 7) << 4)));
            acc[ct] = __builtin_amdgcn_mfma_f32_16x16x32_f16(af, bf, acc[ct], 0, 0, 0);
        }
    }

    // ---- epilogue: dinv-scale, fp16, scattered 2B stores ----
    const int rbase = row0 + 16 * wave + l4 * 4;
    const float d0 = dinv[min(rbase + 0, n - 1)];
    const float d1 = dinv[min(rbase + 1, n - 1)];
    const float d2 = dinv[min(rbase + 2, n - 1)];
    const float d3 = dinv[min(rbase + 3, n - 1)];
#pragma unroll
    for (int ct = 0; ct < NT; ++ct) {
        const int col = ct * 16 + l15;
        if (rbase + 0 < n) C[(size_t)(rbase + 0) * KOUT + col] = __float2half(acc[ct][0] * d0);
        if (rbase + 1 < n) C[(size_t)(rbase + 1) * KOUT + col] = __float2half(acc[ct][1] * d1);
        if (rbase + 2 < n) C[(size_t)(rbase + 2) * KOUT + col] = __float2half(acc[ct][2] * d2);
        if (rbase + 3 < n) C[(size_t)(rbase + 3) * KOUT + col] = __float2half(acc[ct][3] * d3);
    }
}

// ---------------------------------------------------------------------------
// Gather aggregation: fp16 h', one node per 32-lane group, 8-deep batch.
//   out[d][:] = dinv[d] * ( h'[d][:] + sum_{e: dst=d} h'[src_e][:] ) + b
// HOUT: write fp16 (feeds next MFMA gemm); else f32 (final output).
// ---------------------------------------------------------------------------
template<int K, bool HOUT>
__global__ __launch_bounds__(256) void k_aggregate(const __half* __restrict__ h,
                                                   const int* __restrict__ rowstart,
                                                   const int* __restrict__ esrc,
                                                   const float* __restrict__ dinv,
                                                   const float* __restrict__ b,
                                                   void* __restrict__ out, int n) {
    constexpr int VEC = K / 32;            // halves per lane (4 or 2)
    const int tid  = threadIdx.x;
    const int l5   = tid & 31;
    const int base = tid & 32;
    const int node = blockIdx.x * 8 + (tid >> 5);
    if (node >= n) return;

    float a0, a1, a2 = 0.f, a3 = 0.f;
    if (VEC == 4) {
        uint2 raw = ((const uint2*)h)[(size_t)node * 32 + l5];
        union { uint2 u; __half2 h2[2]; } c; c.u = raw;
        float2 lo = __half22float2(c.h2[0]);
        float2 hi = __half22float2(c.h2[1]);
        a0 = lo.x; a1 = lo.y; a2 = hi.x; a3 = hi.y;
    } else {
        uint raw = ((const uint*)h)[(size_t)node * 32 + l5];
        union { uint u; __half2 h2; } c; c.u = raw;
        float2 lo = __half22float2(c.h2);
        a0 = lo.x; a1 = lo.y;
    }

    int row = rowstart[node];
    const int end = rowstart[node + 1];

#define GATHER(SRC_, OK_)                                                     \
    if (VEC == 4) {                                                           \
        uint2 raw = make_uint2(0u, 0u);                                       \
        if (OK_) raw = ((const uint2*)h)[(size_t)(SRC_) * 32 + l5];           \
        union { uint2 u; __half2 h2[2]; } c; c.u = raw;                       \
        float2 lo = __half22float2(c.h2[0]);                                  \
        float2 hi = __half22float2(c.h2[1]);                                  \
        a0 += lo.x; a1 += lo.y; a2 += hi.x; a3 += hi.y;                       \
    } else {                                                                  \
        uint raw = 0u;                                                        \
        if (OK_) raw = ((const uint*)h)[(size_t)(SRC_) * 32 + l5];            \
        union { uint u; __half2 h2; } c; c.u = raw;                           \
        float2 lo = __half22float2(c.h2);                                     \
        a0 += lo.x; a1 += lo.y;                                               \
    }

    while (row < end) {
        int cnt = end - row;
        if (cnt > 32) cnt = 32;
        int s_l = (l5 < cnt) ? esrc[row + l5] : 0;
        for (int jj = 0; jj < cnt; jj += 8) {
            const int i0 = jj + 0, i1 = jj + 1, i2 = jj + 2, i3 = jj + 3;
            const int i4 = jj + 4, i5 = jj + 5, i6 = jj + 6, i7 = jj + 7;
            const int s0 = __shfl(s_l, base + i0);
            const int s1 = __shfl(s_l, base + i1);
            const int s2 = __shfl(s_l, base + i2);
            const int s3 = __shfl(s_l, base + i3);
            const int s4 = __shfl(s_l, base + i4);
            const int s5 = __shfl(s_l, base + i5);
            const int s6 = __shfl(s_l, base + i6);
            const int s7 = __shfl(s_l, base + i7);
            GATHER(s0, i0 < cnt);
            GATHER(s1, i1 < cnt);
            GATHER(s2, i2 < cnt);
            GATHER(s3, i3 < cnt);
            GATHER(s4, i4 < cnt);
            GATHER(s5, i5 < cnt);
            GATHER(s6, i6 < cnt);
            GATHER(s7, i7 < cnt);
        }
        row += cnt;
    }
#undef GATHER

    const float dd = dinv[node];
    if (VEC == 4) {
        float4 bb = ((const float4*)b)[l5];
        float o0 = a0 * dd + bb.x, o1 = a1 * dd + bb.y;
        float o2 = a2 * dd + bb.z, o3 = a3 * dd + bb.w;
        if (HOUT) {
            union { __half2 h2[2]; uint2 u; } pk;
            pk.h2[0] = __floats2half2_rn(o0, o1);
            pk.h2[1] = __floats2half2_rn(o2, o3);
            ((uint2*)out)[(size_t)node * 32 + l5] = pk.u;
        } else {
            ((float4*)out)[(size_t)node * 32 + l5] = make_float4(o0, o1, o2, o3);
        }
    } else {
        float2 bb = ((const float2*)b)[l5];
        float o0 = a0 * dd + bb.x, o1 = a1 * dd + bb.y;
        if (HOUT) {
            union { __half2 h2; uint u; } pk;
            pk.h2 = __floats2half2_rn(o0, o1);
            ((uint*)out)[(size_t)node * 32 + l5] = pk.u;
        } else {
            ((float2*)out)[(size_t)node * 32 + l5] = make_float2(o0, o1);
        }
    }
}

// ---------------------------------------------------------------------------
extern "C" void kernel_launch(void* const* d_in, const int* in_sizes, int n_in,
                              void* d_out, int out_size, void* d_ws, size_t ws_size,
                              hipStream_t stream) {
    const float* x  = (const float*)d_in[0];
    const int*   ei = (const int*)d_in[1];
    const float* W1 = (const float*)d_in[2];
    const float* b1 = (const float*)d_in[3];
    const float* W2 = (const float*)d_in[4];
    const float* b2 = (const float*)d_in[5];
    const float* W3 = (const float*)d_in[6];
    const float* b3 = (const float*)d_in[7];
    float* out = (float*)d_out;

    const int* src = ei;
    const int* dst = ei + N_EDGES;

    char* ws = (char*)d_ws;
    size_t off = 0;
    auto alloc = [&](size_t bytes) {
        void* p = ws + off;
        off += (bytes + 255) & ~(size_t)255;
        return p;
    };
    int*    degcnt   = (int*)alloc((size_t)N_NODES * 2 * 4);  // degcnt + cursor
    int*    cursor   = degcnt + N_NODES;
    int*    rowstart = (int*)alloc((N_NODES + 1) * 4);
    float*  dinv     = (float*)alloc(N_NODES * 4);
    int*    bsum     = (int*)alloc(NB_SCAN * 4);
    int*    boff     = (int*)alloc(NB_SCAN * 4);
    int*    esrc     = (int*)alloc((size_t)N_EDGES * 4);
    __half* hbuf     = (__half*)alloc((size_t)N_NODES * 128 * 2);  // h' fp16
    __half* abuf     = (__half*)alloc((size_t)N_NODES * 128 * 2);  // activations fp16
    __half* wt1      = (__half*)alloc(128 * 128 * 2);
    __half* wt2      = (__half*)alloc(128 * 128 * 2);
    __half* wt3      = (__half*)alloc(64 * 128 * 2);

    const int n = N_NODES, e = N_EDGES;
    const int e4 = e / 4;

    // --- CSR build (dst-partitioned; once, reused by all layers) ---
    hipMemsetAsync(degcnt, 0, (size_t)N_NODES * 2 * 4, stream);
    k_deg4p<<<CEILDIV(e4, 256) * NPART, 256, 0, stream>>>(dst, degcnt, e4);
    k_blocksum<<<NB_SCAN, 256, 0, stream>>>(degcnt, bsum, n);
    k_scanb<<<1, 256, 0, stream>>>(bsum, boff);
    k_rowstart<<<NB_SCAN, 256, 0, stream>>>(degcnt, boff, rowstart, dinv, n);
    k_bin4p<<<CEILDIV(e4, 256) * NPART, 256, 0, stream>>>(src, dst, rowstart, cursor, esrc, e4);

    // --- one-time W casts ---
    k_wcast<<<CEILDIV(40960, 256), 256, 0, stream>>>(W1, W2, W3, wt1, wt2, wt3);

    // --- layer 1 (x cast fused into GEMM staging) ---
    k_gemm<128, false, true><<<CEILDIV(n, 64), 256, 0, stream>>>(x, wt1, dinv, hbuf, n);
    k_aggregate<128, true><<<CEILDIV(n, 8), 256, 0, stream>>>(hbuf, rowstart, esrc, dinv, b1, abuf, n);

    // --- layer 2 ---
    k_gemm<128, true, false><<<CEILDIV(n, 64), 256, 0, stream>>>(abuf, wt2, dinv, hbuf, n);
    k_aggregate<128, true><<<CEILDIV(n, 8), 256, 0, stream>>>(hbuf, rowstart, esrc, dinv, b2, abuf, n);

    // --- layer 3 (K=64) ---
    k_gemm<64, true, false><<<CEILDIV(n, 64), 256, 0, stream>>>(abuf, wt3, dinv, hbuf, n);
    k_aggregate<64, false><<<CEILDIV(n, 8), 256, 0, stream>>>(hbuf, rowstart, esrc, dinv, b3, out, n);
}